// Round 1
// baseline (340.080 us; speedup 1.0000x reference)
//
#include <hip/hip_runtime.h>

#define LOG2E 1.44269504088896340736f

typedef __bf16 bf16x8 __attribute__((ext_vector_type(8)));
typedef float f32x16 __attribute__((ext_vector_type(16)));

union U4B { uint4 u; bf16x8 v; };

static __device__ __forceinline__ unsigned short f2bf(float f) {
  unsigned u = __builtin_bit_cast(unsigned, f);
  u += 0x7FFFu + ((u >> 16) & 1u);
  return (unsigned short)(u >> 16);
}
static __device__ __forceinline__ float bf2f(unsigned short s) {
  unsigned u = ((unsigned)s) << 16;
  return __builtin_bit_cast(float, u);
}
static __device__ __forceinline__ f32x16 zero16() {
  f32x16 z;
#pragma unroll
  for (int i = 0; i < 16; ++i) z[i] = 0.f;
  return z;
}
static __device__ __forceinline__ f32x16 MFMA(bf16x8 a, bf16x8 b, f32x16 c) {
  return __builtin_amdgcn_mfma_f32_32x32x16_bf16(a, b, c, 0, 0, 0);
}

// Transform a 32x32 C/D-layout f32x16 tile (lane: col=l&31, row=(r&3)+8*(r>>2)+4*hi)
// into two bf16x8 frags: frag[ch] elem e = T[16*ch + 8*hi + e][col].
static __device__ __forceinline__ void xform(f32x16 t, int hi, uint4& f0, uint4& f1) {
  unsigned pk[8], sw[8];
#pragma unroll
  for (int s = 0; s < 8; ++s) {
    unsigned d;
    asm("v_cvt_pk_bf16_f32 %0, %1, %2" : "=v"(d) : "v"(t[2*s]), "v"(t[2*s+1]));
    pk[s] = d;
  }
#pragma unroll
  for (int s = 0; s < 8; ++s) sw[s] = (unsigned)__shfl_xor((int)pk[s], 32);
  if (hi) {
    f0 = make_uint4(sw[2], sw[3], pk[2], pk[3]);
    f1 = make_uint4(sw[6], sw[7], pk[6], pk[7]);
  } else {
    f0 = make_uint4(pk[0], pk[1], sw[0], sw[1]);
    f1 = make_uint4(pk[4], pk[5], sw[4], sw[5]);
  }
}

__global__ void setup_k(
    const float* __restrict__ wq_w, const float* __restrict__ wq_b,
    const float* __restrict__ wk_w, const float* __restrict__ wk_b,
    const float* __restrict__ wv_w, const float* __restrict__ wv_b,
    const float* __restrict__ dense_w, float* __restrict__ ws)
{
  int gid = blockIdx.x*256 + threadIdx.x;
  float* pe = ws;                                        // 2560 f32
  unsigned short* wqT = (unsigned short*)(ws + 2560);    // [512][32] bf16 (t<20 w, t==20 bias, else 0)
  unsigned short* wkT = (unsigned short*)(ws + 10752);
  float* WVD = ws + 18944;                               // [8][10][10]
  float* bvd = ws + 19744;                               // [8][10]
  if (gid < 2560) {
    int i = gid/10, t = gid%10;
    double ex = (double)(2*(t/2)) / 10.0;
    double ang = (double)i * pow(10000.0, -ex);
    pe[gid] = (float)((t & 1) ? cos(ang) : sin(ang));
  } else if (gid < 2560 + 16384) {
    int idx = gid - 2560;
    int hd = idx >> 5, t = idx & 31;
    float v = (t < 20) ? wq_w[t*512 + hd] : ((t == 20) ? wq_b[hd] : 0.f);
    wqT[idx] = f2bf(v);
  } else if (gid < 2560 + 32768) {
    int idx = gid - (2560 + 16384);
    int hd = idx >> 5, t = idx & 31;
    float v = (t < 20) ? wk_w[t*512 + hd] : ((t == 20) ? wk_b[hd] : 0.f);
    wkT[idx] = f2bf(v);
  } else if (gid < 2560 + 32768 + 800) {
    int idx = gid - (2560 + 32768);
    int h = idx/100, rem = idx%100, t = rem/10, w = rem%10;
    float s = 0.f;
    for (int d = 0; d < 64; ++d) s += wv_w[t*512 + h*64 + d] * dense_w[(h*64 + d)*10 + w];
    WVD[idx] = s;
  } else if (gid < 2560 + 32768 + 880) {
    int idx = gid - (2560 + 32768 + 800);
    int h = idx/10, w = idx%10;
    float s = 0.f;
    for (int d = 0; d < 64; ++d) s += wv_b[h*64 + d] * dense_w[(h*64 + d)*10 + w];
    bvd[idx] = s;
  }
}

__global__ __launch_bounds__(256, 1) void mha_fused(
    const float* __restrict__ x,
    const float* __restrict__ dense_w, const float* __restrict__ dense_b,
    const unsigned short* __restrict__ wqT, const unsigned short* __restrict__ wkT,
    const float* __restrict__ WVD, const float* __restrict__ bvd,
    const float* __restrict__ pe,
    float* __restrict__ out)
{
  __shared__ __align__(16) unsigned short qk_in[256*24];  // [win][24] bf16: dd[i+2](10), dd[i](10), 1.0, 0,0,0
  __shared__ __align__(16) unsigned short k_lds[256*64];  // [key][64] bf16, 16B-granule XOR (key&7)
  __shared__ __align__(16) unsigned short vdT[32*256];    // [w][key] bf16, granule XOR (w&15)
  __shared__ float mean_l[256];
  __shared__ unsigned long long padb[4];

  const int tid = threadIdx.x;
  const int lane = tid & 63;
  const int wv = tid >> 6;
  const int hi = lane >> 5;
  const int cc = lane & 31;
  const int bc = blockIdx.x;

  // ---- Phase A: load x, mean/minmask, dd = data+pe, build qk_in + padbits ----
  float ddr[10];
  {
    const float* xb = x + ((size_t)bc*2560 + tid*10)*3;
    float dat[10], msk[10];
#pragma unroll
    for (int t = 0; t < 10; ++t) { dat[t] = xb[3*t]; msk[t] = xb[3*t+2]; }
    float mean = 0.f, mm = msk[0];
#pragma unroll
    for (int t = 0; t < 10; ++t) { mean += dat[t]*msk[t]; mm = fminf(mm, msk[t]); }
    mean_l[tid] = mean * 0.1f;
    const float* per = pe + tid*10;
#pragma unroll
    for (int t = 0; t < 10; ++t) ddr[t] = dat[t] + per[t];
    float* ddtmp = (float*)k_lds;        // alias k_lds during phase A
    float* mmv = ddtmp + 2560;
#pragma unroll
    for (int t = 0; t < 10; ++t) ddtmp[tid*10 + t] = ddr[t];
    mmv[tid] = mm;
  }
  __syncthreads();
  {
    const float* ddtmp = (const float*)k_lds;
    const float* mmv = ddtmp + 2560;
    if (tid < 254) {
#pragma unroll
      for (int t = 0; t < 10; ++t) qk_in[tid*24 + t] = f2bf(ddtmp[(tid+2)*10 + t]);
#pragma unroll
      for (int t = 0; t < 10; ++t) qk_in[tid*24 + 10 + t] = f2bf(ddr[t]);
      qk_in[tid*24 + 20] = 0x3F80;   // bias 1.0
      qk_in[tid*24 + 21] = 0; qk_in[tid*24 + 22] = 0; qk_in[tid*24 + 23] = 0;
    } else {
#pragma unroll
      for (int t = 0; t < 24; ++t) qk_in[tid*24 + t] = 0;
    }
    bool cond = (tid < 254) && (mmv[tid+1] == 0.0f);   // padding[key=tid] from window tid+1
    unsigned long long bl = __ballot(cond);
    if (lane == 0) padb[wv] = bl;
  }
  __syncthreads();
  unsigned pb[8];
  {
    const unsigned* pw = (const unsigned*)padb;
#pragma unroll
    for (int j = 0; j < 8; ++j) pb[j] = pw[j];
  }
  float dwcol = 0.f, dbias = 0.f;
  if (cc < 10) { dwcol = dense_w[5120 + cc]; dbias = dense_b[cc]; }

  f32x16 outacc0 = zero16(), outacc1 = zero16();

#pragma unroll 1
  for (int h = 0; h < 8; ++h) {
    __syncthreads();   // prior head's attention reads done
    // ---- stage VD^T = (dd[1..254] @ WVD_h + bvd_h)^T, bf16, swizzled ----
    if (tid < 254) {
      float df[10];
      int src = tid + 1;
      if (src <= 253) {
#pragma unroll
        for (int t = 0; t < 10; ++t) df[t] = bf2f(qk_in[src*24 + 10 + t]);   // dd[src]
      } else {
#pragma unroll
        for (int t = 0; t < 10; ++t) df[t] = bf2f(qk_in[252*24 + t]);        // dd[254]
      }
      const float* wvd = WVD + h*100;
      const float* bv = bvd + h*10;
#pragma unroll
      for (int w = 0; w < 10; ++w) {
        float s = bv[w];
#pragma unroll
        for (int t = 0; t < 10; ++t) s += df[t]*wvd[t*10 + w];
        vdT[w*256 + (tid ^ ((w & 15)*8))] = f2bf(s);
      }
    }
    if (tid < 64) {   // zero pad-keys 254/255 in all 32 w-rows (avoid NaN*0 in mfma)
      int w = tid >> 1, j = 254 + (tid & 1);
      vdT[w*256 + (j ^ ((w & 15)*8))] = 0;
    }
    __syncthreads();

    // ---- K projection (swapped): KT = WK'_h x qk_in^T, write A-frags to k_lds ----
#pragma unroll
    for (int jti = 0; jti < 2; ++jti) {
      int jt = wv + 4*jti;
      int krow = 32*jt + cc;
      U4B b0, b1;
      b0.u = *(const uint4*)&qk_in[krow*24 + 8*hi];
      b1.u = make_uint4(0,0,0,0);
      if (!hi) b1.u = *(const uint4*)&qk_in[krow*24 + 16];
#pragma unroll
      for (int it = 0; it < 2; ++it) {
        const unsigned short* wrow = wkT + (h*64 + 32*it + cc)*32;
        U4B a0, a1;
        a0.u = *(const uint4*)&wrow[8*hi];
        a1.u = *(const uint4*)&wrow[16 + 8*hi];
        f32x16 acc = zero16();
        acc = MFMA(a0.v, b0.v, acc);
        acc = MFMA(a1.v, b1.v, acc);
        uint4 f0, f1;
        xform(acc, hi, f0, f1);
        int dc0 = 2*it, dc1 = 2*it + 1;
        *(uint4*)&k_lds[krow*64 + ((8*(2*dc0 + hi)) ^ (8*(krow & 7)))] = f0;
        *(uint4*)&k_lds[krow*64 + ((8*(2*dc1 + hi)) ^ (8*(krow & 7)))] = f1;
      }
    }
    __syncthreads();

    // ---- attention: each wave handles query tiles wv and wv+4 ----
#pragma unroll
    for (int qti = 0; qti < 2; ++qti) {
      int qt = wv + 4*qti;
      int qrow = 32*qt + cc;
      // Q projection (swapped) -> B-frags in regs
      uint4 qf[4];
      {
        U4B b0, b1;
        b0.u = *(const uint4*)&qk_in[qrow*24 + 8*hi];
        b1.u = make_uint4(0,0,0,0);
        if (!hi) b1.u = *(const uint4*)&qk_in[qrow*24 + 16];
#pragma unroll
        for (int it = 0; it < 2; ++it) {
          const unsigned short* wrow = wqT + (h*64 + 32*it + cc)*32;
          U4B a0, a1;
          a0.u = *(const uint4*)&wrow[8*hi];
          a1.u = *(const uint4*)&wrow[16 + 8*hi];
          f32x16 acc = zero16();
          acc = MFMA(a0.v, b0.v, acc);
          acc = MFMA(a1.v, b1.v, acc);
          xform(acc, hi, qf[2*it], qf[2*it + 1]);
        }
      }
      // S^T tiles over all 8 key tiles (full row materialized)
      f32x16 st[8];
#pragma unroll
      for (int kt = 0; kt < 8; ++kt) {
        int kr = 32*kt + cc;
        f32x16 a = zero16();
#pragma unroll
        for (int dc = 0; dc < 4; ++dc) {
          U4B ka, qa;
          ka.u = *(const uint4*)&k_lds[kr*64 + ((8*(2*dc + hi)) ^ (8*(kr & 7)))];
          qa.u = qf[dc];
          a = MFMA(ka.v, qa.v, a);
        }
        st[kt] = a;
      }
      // scale + mask (matches reference's fp32 -1e9 absorption exactly)
#pragma unroll
      for (int kt = 0; kt < 8; ++kt) {
#pragma unroll
        for (int r = 0; r < 16; ++r) {
          const int base = (r & 3) + 8*(r >> 2);
          int key = 32*kt + base + 4*hi;
          bool mk = (key > qrow) || (((pb[kt] >> (base + 4*hi)) & 1u) != 0u);
          float mv = mk ? -1e9f : 0.f;
          if (kt == 7 && r >= 14) mv = hi ? -1e30f : mv;   // pad keys 254/255
          st[kt][r] = st[kt][r]*0.125f + mv;
        }
      }
      // softmax (per query = lane cc, both halves merged via shfl_xor 32)
      float m = st[0][0];
#pragma unroll
      for (int kt = 0; kt < 8; ++kt) {
#pragma unroll
        for (int r = 0; r < 16; ++r) m = fmaxf(m, st[kt][r]);
      }
      m = fmaxf(m, __shfl_xor(m, 32));
      float mL = m * LOG2E;
      float sum = 0.f;
#pragma unroll
      for (int kt = 0; kt < 8; ++kt) {
        float sk = 0.f;
#pragma unroll
        for (int r = 0; r < 16; ++r) {
          float p = exp2f(fmaf(st[kt][r], LOG2E, -mL));
          st[kt][r] = p;
          sk += p;
        }
        sum += sk;
      }
      sum += __shfl_xor(sum, 32);
      float rs = 1.0f / sum;
      // PV: out10 += P @ VD  (unnormalized; scaled by 1/sum at accumulate)
      f32x16 pv = zero16();
#pragma unroll
      for (int kt = 0; kt < 8; ++kt) {
        uint4 pa0, pa1;
        xform(st[kt], hi, pa0, pa1);
        U4B pA, vB;
        pA.u = pa0;
        vB.u = *(const uint4*)&vdT[cc*256 + ((32*kt + 8*hi) ^ (8*(cc & 15)))];
        pv = MFMA(pA.v, vB.v, pv);
        pA.u = pa1;
        vB.u = *(const uint4*)&vdT[cc*256 + ((32*kt + 16 + 8*hi) ^ (8*(cc & 15)))];
        pv = MFMA(pA.v, vB.v, pv);
      }
#pragma unroll
      for (int r = 0; r < 16; ++r) {
        const int base = (r & 3) + 8*(r >> 2);
        float rr = __shfl(rs, base + 4*hi, 32);
        if (qti == 0) outacc0[r] += pv[r]*rr; else outacc1[r] += pv[r]*rr;
      }
    }
  }

  // ---- epilogue: + mean_feature * dense_w[512] + dense_b ----
#pragma unroll
  for (int qti = 0; qti < 2; ++qti) {
#pragma unroll
    for (int r = 0; r < 16; ++r) {
      const int base = (r & 3) + 8*(r >> 2);
      int q = 32*(wv + 4*qti) + base + 4*hi;
      if (q < 254 && cc < 10) {
        float v = (qti == 0 ? outacc0[r] : outacc1[r]) + mean_l[q + 1]*dwcol + dbias;
        out[((size_t)bc*254 + q)*10 + cc] = v;
      }
    }
  }
}

extern "C" void kernel_launch(void* const* d_in, const int* in_sizes, int n_in,
                              void* d_out, int out_size, void* d_ws, size_t ws_size,
                              hipStream_t stream) {
  const float* x       = (const float*)d_in[0];
  const float* wq_w    = (const float*)d_in[1];
  const float* wq_b    = (const float*)d_in[2];
  const float* wk_w    = (const float*)d_in[3];
  const float* wk_b    = (const float*)d_in[4];
  const float* wv_w    = (const float*)d_in[5];
  const float* wv_b    = (const float*)d_in[6];
  const float* dense_w = (const float*)d_in[7];
  const float* dense_b = (const float*)d_in[8];
  float* ws = (float*)d_ws;

  setup_k<<<142, 256, 0, stream>>>(wq_w, wq_b, wk_w, wk_b, wv_w, wv_b, dense_w, ws);
  mha_fused<<<256, 256, 0, stream>>>(
      x, dense_w, dense_b,
      (const unsigned short*)(ws + 2560),   // wqT
      (const unsigned short*)(ws + 10752),  // wkT
      ws + 18944,                           // WVD
      ws + 19744,                           // bvd
      ws,                                   // pe
      (float*)d_out);
}

// Round 3
// 220.534 us; speedup vs baseline: 1.5421x; 1.5421x over previous
//
#include <hip/hip_runtime.h>

#define LOG2E 1.44269504088896340736f

typedef __bf16 bf16x8 __attribute__((ext_vector_type(8)));
typedef float f32x16 __attribute__((ext_vector_type(16)));

union U4B { uint4 u; bf16x8 v; };

static __device__ __forceinline__ unsigned short f2bf(float f) {
  unsigned u = __builtin_bit_cast(unsigned, f);
  u += 0x7FFFu + ((u >> 16) & 1u);
  return (unsigned short)(u >> 16);
}
static __device__ __forceinline__ float bf2f(unsigned short s) {
  unsigned u = ((unsigned)s) << 16;
  return __builtin_bit_cast(float, u);
}
static __device__ __forceinline__ f32x16 zero16() {
  f32x16 z;
#pragma unroll
  for (int i = 0; i < 16; ++i) z[i] = 0.f;
  return z;
}
static __device__ __forceinline__ f32x16 MFMA(bf16x8 a, bf16x8 b, f32x16 c) {
  return __builtin_amdgcn_mfma_f32_32x32x16_bf16(a, b, c, 0, 0, 0);
}

// Transform a 32x32 C/D-layout f32x16 tile (lane: col=l&31, row=(r&3)+8*(r>>2)+4*hi)
// into two bf16x8 frags: frag[ch] elem e = T[16*ch + 8*hi + e][col].
static __device__ __forceinline__ void xform(f32x16 t, int hi, uint4& f0, uint4& f1) {
  unsigned pk[8], sw[8];
#pragma unroll
  for (int s = 0; s < 8; ++s) {
    unsigned d;
    asm("v_cvt_pk_bf16_f32 %0, %1, %2" : "=v"(d) : "v"(t[2*s]), "v"(t[2*s+1]));
    pk[s] = d;
  }
#pragma unroll
  for (int s = 0; s < 8; ++s) sw[s] = (unsigned)__shfl_xor((int)pk[s], 32);
  if (hi) {
    f0 = make_uint4(sw[2], sw[3], pk[2], pk[3]);
    f1 = make_uint4(sw[6], sw[7], pk[6], pk[7]);
  } else {
    f0 = make_uint4(pk[0], pk[1], sw[0], sw[1]);
    f1 = make_uint4(pk[4], pk[5], sw[4], sw[5]);
  }
}

__global__ void zero_out_k(float* __restrict__ out, int n) {
  int i = blockIdx.x * 256 + threadIdx.x;
  if (i < n) out[i] = 0.f;
}

__global__ void setup_k(
    const float* __restrict__ wq_w, const float* __restrict__ wq_b,
    const float* __restrict__ wk_w, const float* __restrict__ wk_b,
    const float* __restrict__ wv_w, const float* __restrict__ wv_b,
    const float* __restrict__ dense_w, float* __restrict__ ws)
{
  int gid = blockIdx.x*256 + threadIdx.x;
  float* pe = ws;                                        // 2560 f32
  unsigned short* wqT = (unsigned short*)(ws + 2560);    // [512][32] bf16 (t<20 w, t==20 bias, else 0)
  unsigned short* wkT = (unsigned short*)(ws + 10752);
  float* WVD = ws + 18944;                               // [8][10][10]
  float* bvd = ws + 19744;                               // [8][10]
  if (gid < 2560) {
    int i = gid/10, t = gid%10;
    double ex = (double)(2*(t/2)) / 10.0;
    double ang = (double)i * pow(10000.0, -ex);
    pe[gid] = (float)((t & 1) ? cos(ang) : sin(ang));
  } else if (gid < 2560 + 16384) {
    int idx = gid - 2560;
    int hd = idx >> 5, t = idx & 31;
    float v = (t < 20) ? wq_w[t*512 + hd] : ((t == 20) ? wq_b[hd] : 0.f);
    wqT[idx] = f2bf(v);
  } else if (gid < 2560 + 32768) {
    int idx = gid - (2560 + 16384);
    int hd = idx >> 5, t = idx & 31;
    float v = (t < 20) ? wk_w[t*512 + hd] : ((t == 20) ? wk_b[hd] : 0.f);
    wkT[idx] = f2bf(v);
  } else if (gid < 2560 + 32768 + 800) {
    int idx = gid - (2560 + 32768);
    int h = idx/100, rem = idx%100, t = rem/10, w = rem%10;
    float s = 0.f;
    for (int d = 0; d < 64; ++d) s += wv_w[t*512 + h*64 + d] * dense_w[(h*64 + d)*10 + w];
    WVD[idx] = s;
  } else if (gid < 2560 + 32768 + 880) {
    int idx = gid - (2560 + 32768 + 800);
    int h = idx/10, w = idx%10;
    float s = 0.f;
    for (int d = 0; d < 64; ++d) s += wv_b[h*64 + d] * dense_w[(h*64 + d)*10 + w];
    bvd[idx] = s;
  }
}

// Grid 512: block = (bc, parity). parity p handles heads p*4..p*4+3, atomicAdd to out.
__global__ __launch_bounds__(256, 1) void mha_fused(
    const float* __restrict__ x,
    const float* __restrict__ dense_w, const float* __restrict__ dense_b,
    const unsigned short* __restrict__ wqT, const unsigned short* __restrict__ wkT,
    const float* __restrict__ WVD, const float* __restrict__ bvd,
    const float* __restrict__ pe,
    float* __restrict__ out)
{
  __shared__ __align__(16) unsigned short qk_in[256*24];  // [win][24] bf16: dd[i+2](10), dd[i](10), 1.0, 0,0,0
  __shared__ __align__(16) unsigned short k_lds[256*64];  // [key][64] bf16 A-frags, 16B-granule XOR (key&7)
  __shared__ __align__(16) unsigned short vdT[32*256];    // [w][key] bf16, granule XOR (w&15)
  __shared__ float mean_l[256];
  __shared__ unsigned long long padb[4];
  __shared__ float part[160];
  __shared__ float ddmean_s[10];

  const int tid = threadIdx.x;
  const int lane = tid & 63;
  const int wv = tid >> 6;
  const int hi = lane >> 5;
  const int cc = lane & 31;
  const int bc = blockIdx.x >> 1;
  const int parity = blockIdx.x & 1;

  // ---- Phase A: load x, mean/minmask, dd = data+pe, build qk_in + padbits + ddmean ----
  float ddr[10];
  {
    const float* xb = x + ((size_t)bc*2560 + tid*10)*3;
    float dat[10], msk[10];
#pragma unroll
    for (int t = 0; t < 10; ++t) { dat[t] = xb[3*t]; msk[t] = xb[3*t+2]; }
    float mean = 0.f, mm = msk[0];
#pragma unroll
    for (int t = 0; t < 10; ++t) { mean += dat[t]*msk[t]; mm = fminf(mm, msk[t]); }
    mean_l[tid] = mean * 0.1f;
    const float* per = pe + tid*10;
#pragma unroll
    for (int t = 0; t < 10; ++t) ddr[t] = dat[t] + per[t];
    float* ddtmp = (float*)k_lds;        // alias k_lds during phase A
    float* mmv = ddtmp + 2560;
#pragma unroll
    for (int t = 0; t < 10; ++t) ddtmp[tid*10 + t] = ddr[t];
    mmv[tid] = mm;
  }
  __syncthreads();
  {
    const float* ddtmp = (const float*)k_lds;
    const float* mmv = ddtmp + 2560;
    if (tid < 254) {
#pragma unroll
      for (int t = 0; t < 10; ++t) qk_in[tid*24 + t] = f2bf(ddtmp[(tid+2)*10 + t]);
#pragma unroll
      for (int t = 0; t < 10; ++t) qk_in[tid*24 + 10 + t] = f2bf(ddr[t]);
      qk_in[tid*24 + 20] = 0x3F80;   // bias 1.0
      qk_in[tid*24 + 21] = 0; qk_in[tid*24 + 22] = 0; qk_in[tid*24 + 23] = 0;
    } else {
#pragma unroll
      for (int t = 0; t < 24; ++t) qk_in[tid*24 + t] = 0;
    }
    // partial sums for ddmean (mean over dd[1..254])
    if (tid < 160) {
      int t = tid >> 4, j = tid & 15;
      int w0 = 1 + j*16, w1 = (w0 + 16 < 255) ? (w0 + 16) : 255;
      float s = 0.f;
      for (int w = w0; w < w1; ++w) s += ddtmp[w*10 + t];
      part[tid] = s;
    }
    bool cond = (tid < 254) && (mmv[tid+1] == 0.0f);   // padding[key=tid] from window tid+1
    unsigned long long bl = __ballot(cond);
    if (lane == 0) padb[wv] = bl;
  }
  __syncthreads();
  if (tid < 10) {
    float s = 0.f;
#pragma unroll
    for (int j = 0; j < 16; ++j) s += part[tid*16 + j];
    ddmean_s[tid] = s * (1.0f/254.0f);
  }
  float dwcol = 0.f, dbias = 0.f;
  if (cc < 10) { dwcol = dense_w[5120 + cc]; dbias = dense_b[cc]; }
  const unsigned* pw = (const unsigned*)padb;

  f32x16 outacc0 = zero16(), outacc1 = zero16();

#pragma unroll 1
  for (int hh = 0; hh < 4; ++hh) {
    const int h = parity*4 + hh;
    __syncthreads();   // prior head's attention reads done (and phase-A LDS ready)
    // ---- stage VD^T = (dd[1..254] @ WVD_h + bvd_h)^T, bf16, swizzled ----
    if (tid < 254) {
      float df[10];
      int src = tid + 1;
      if (src <= 253) {
#pragma unroll
        for (int t = 0; t < 10; ++t) df[t] = bf2f(qk_in[src*24 + 10 + t]);   // dd[src]
      } else {
#pragma unroll
        for (int t = 0; t < 10; ++t) df[t] = bf2f(qk_in[252*24 + t]);        // dd[254]
      }
      const float* wvd = WVD + h*100;
      const float* bv = bvd + h*10;
#pragma unroll
      for (int w = 0; w < 10; ++w) {
        float s = bv[w];
#pragma unroll
        for (int t = 0; t < 10; ++t) s += df[t]*wvd[t*10 + w];
        vdT[w*256 + (tid ^ ((w & 15)*8))] = f2bf(s);
      }
    }
    if (tid < 64) {   // zero pad-keys 254/255 in all 32 w-rows (avoid NaN*0 in mfma)
      int w = tid >> 1, j = 254 + (tid & 1);
      vdT[w*256 + (j ^ ((w & 15)*8))] = 0;
    }
    // meanVD for degenerate (fully-padded) query rows: colmean of VD_h
    float mvd = 0.f;
    if (cc < 10) {
      mvd = bvd[h*10 + cc];
#pragma unroll
      for (int t = 0; t < 10; ++t) mvd = fmaf(ddmean_s[t], WVD[h*100 + t*10 + cc], mvd);
    }
    __syncthreads();

    // ---- K projection (swapped): KT = WK'_h x qk_in^T, write A-frags to k_lds ----
#pragma unroll
    for (int jti = 0; jti < 2; ++jti) {
      int jt = wv + 4*jti;
      int krow = 32*jt + cc;
      U4B b0, b1;
      b0.u = *(const uint4*)&qk_in[krow*24 + 8*hi];
      b1.u = make_uint4(0,0,0,0);
      if (!hi) b1.u = *(const uint4*)&qk_in[krow*24 + 16];
#pragma unroll
      for (int it = 0; it < 2; ++it) {
        const unsigned short* wrow = wkT + (h*64 + 32*it + cc)*32;
        U4B a0, a1;
        a0.u = *(const uint4*)&wrow[8*hi];
        a1.u = *(const uint4*)&wrow[16 + 8*hi];
        f32x16 acc = zero16();
        acc = MFMA(a0.v, b0.v, acc);
        acc = MFMA(a1.v, b1.v, acc);
        uint4 f0, f1;
        xform(acc, hi, f0, f1);
        int dc0 = 2*it, dc1 = 2*it + 1;
        *(uint4*)&k_lds[krow*64 + ((8*(2*dc0 + hi)) ^ (8*(krow & 7)))] = f0;
        *(uint4*)&k_lds[krow*64 + ((8*(2*dc1 + hi)) ^ (8*(krow & 7)))] = f1;
      }
    }
    __syncthreads();

    // ---- attention: wave wv owns query tiles {wv, 7-wv} (causal work = 9 tiles, balanced) ----
#pragma unroll
    for (int qti = 0; qti < 2; ++qti) {
      const int qt = qti ? (7 - wv) : wv;
      const int qrow = 32*qt + cc;
      // Q projection (swapped) -> B-frags in regs
      uint4 qf0, qf1, qf2, qf3;
      {
        U4B b0, b1;
        b0.u = *(const uint4*)&qk_in[qrow*24 + 8*hi];
        b1.u = make_uint4(0,0,0,0);
        if (!hi) b1.u = *(const uint4*)&qk_in[qrow*24 + 16];
        {
          const unsigned short* wrow = wqT + (h*64 + cc)*32;
          U4B a0, a1;
          a0.u = *(const uint4*)&wrow[8*hi];
          a1.u = *(const uint4*)&wrow[16 + 8*hi];
          f32x16 acc = zero16();
          acc = MFMA(a0.v, b0.v, acc);
          acc = MFMA(a1.v, b1.v, acc);
          xform(acc, hi, qf0, qf1);
        }
        {
          const unsigned short* wrow = wqT + (h*64 + 32 + cc)*32;
          U4B a0, a1;
          a0.u = *(const uint4*)&wrow[8*hi];
          a1.u = *(const uint4*)&wrow[16 + 8*hi];
          f32x16 acc = zero16();
          acc = MFMA(a0.v, b0.v, acc);
          acc = MFMA(a1.v, b1.v, acc);
          xform(acc, hi, qf2, qf3);
        }
      }
      // ---- S^T tiles over causal key tiles only (kt <= qt), stored (round-1 numerics) ----
      f32x16 st[8];
#pragma unroll
      for (int kt = 0; kt < 8; ++kt) {
        if (kt <= qt) {
          const int kr = 32*kt + cc;
          const int kbase = kr*64;
          const int ksw = 8*(kr & 7);
          f32x16 a = zero16();
          U4B ka, qa;
          ka.u = *(const uint4*)&k_lds[kbase + ((8*(0 + hi)) ^ ksw)];
          qa.u = qf0; a = MFMA(ka.v, qa.v, a);
          ka.u = *(const uint4*)&k_lds[kbase + ((8*(2 + hi)) ^ ksw)];
          qa.u = qf1; a = MFMA(ka.v, qa.v, a);
          ka.u = *(const uint4*)&k_lds[kbase + ((8*(4 + hi)) ^ ksw)];
          qa.u = qf2; a = MFMA(ka.v, qa.v, a);
          ka.u = *(const uint4*)&k_lds[kbase + ((8*(6 + hi)) ^ ksw)];
          qa.u = qf3; a = MFMA(ka.v, qa.v, a);
          const unsigned pbk = pw[kt];
#pragma unroll
          for (int r = 0; r < 16; ++r) {
            const int base = (r & 3) + 8*(r >> 2);
            const int key = 32*kt + base + 4*hi;
            bool mk = (key > qrow) || (((pbk >> (base + 4*hi)) & 1u) != 0u);
            float mv = mk ? -1e9f : 0.f;
            if (kt == 7 && r >= 14) mv = hi ? -1e30f : mv;   // pad keys 254/255
            a[r] = a[r]*0.125f + mv;
          }
          st[kt] = a;
        }
      }
      // ---- softmax (two-pass over stored tiles; per query = lane cc, halves via shfl_xor 32) ----
      float m = st[0][0];
#pragma unroll
      for (int kt = 0; kt < 8; ++kt) {
        if (kt <= qt) {
#pragma unroll
          for (int r = 0; r < 16; ++r) m = fmaxf(m, st[kt][r]);
        }
      }
      m = fmaxf(m, __shfl_xor(m, 32));
      const float mL = m * LOG2E;
      float sum = 0.f;
#pragma unroll
      for (int kt = 0; kt < 8; ++kt) {
        if (kt <= qt) {
          float sk = 0.f;
#pragma unroll
          for (int r = 0; r < 16; ++r) {
            float p = exp2f(fmaf(st[kt][r], LOG2E, -mL));
            st[kt][r] = p;
            sk += p;
          }
          sum += sk;
        }
      }
      sum += __shfl_xor(sum, 32);
      const float rs = 1.0f / sum;
      // ---- PV over causal tiles ----
      f32x16 pv = zero16();
#pragma unroll
      for (int kt = 0; kt < 8; ++kt) {
        if (kt <= qt) {
          uint4 pa0, pa1;
          xform(st[kt], hi, pa0, pa1);
          U4B pA, vB;
          pA.u = pa0;
          vB.u = *(const uint4*)&vdT[cc*256 + ((32*kt + 8*hi) ^ (8*(cc & 15)))];
          pv = MFMA(pA.v, vB.v, pv);
          pA.u = pa1;
          vB.u = *(const uint4*)&vdT[cc*256 + ((32*kt + 16 + 8*hi) ^ (8*(cc & 15)))];
          pv = MFMA(pA.v, vB.v, pv);
        }
      }
      // ---- degenerate (all keys <= q padded) -> substitute column-mean of VD ----
      bool pre = true;
#pragma unroll
      for (int j = 0; j < 8; ++j) { if (j < qt) pre = pre && (pw[j] == 0xFFFFFFFFu); }
      const unsigned pbq = pw[qt];
#pragma unroll
      for (int r = 0; r < 16; ++r) {
        const int base = (r & 3) + 8*(r >> 2);
        const int qr = base + 4*hi;
        unsigned lm = (qr == 31) ? 0xFFFFFFFFu : ((2u << qr) - 1u);
        bool degq = pre && ((pbq & lm) == lm);
        float rr = __shfl(rs, qr, 32);
        float contrib = degq ? mvd : pv[r]*rr;
        if (qti == 0) outacc0[r] += contrib; else outacc1[r] += contrib;
      }
    }
  }

  // ---- epilogue: atomicAdd partial (4-head) sums; parity 0 adds mean term + bias ----
#pragma unroll
  for (int qti = 0; qti < 2; ++qti) {
    const int qt = qti ? (7 - wv) : wv;
#pragma unroll
    for (int r = 0; r < 16; ++r) {
      const int base = (r & 3) + 8*(r >> 2);
      int q = 32*qt + base + 4*hi;
      if (q < 254 && cc < 10) {
        float v = (qti == 0 ? outacc0[r] : outacc1[r]);
        if (parity == 0) v += mean_l[q + 1]*dwcol + dbias;
        atomicAdd(&out[((size_t)bc*254 + q)*10 + cc], v);
      }
    }
  }
}

extern "C" void kernel_launch(void* const* d_in, const int* in_sizes, int n_in,
                              void* d_out, int out_size, void* d_ws, size_t ws_size,
                              hipStream_t stream) {
  const float* x       = (const float*)d_in[0];
  const float* wq_w    = (const float*)d_in[1];
  const float* wq_b    = (const float*)d_in[2];
  const float* wk_w    = (const float*)d_in[3];
  const float* wk_b    = (const float*)d_in[4];
  const float* wv_w    = (const float*)d_in[5];
  const float* wv_b    = (const float*)d_in[6];
  const float* dense_w = (const float*)d_in[7];
  const float* dense_b = (const float*)d_in[8];
  float* ws = (float*)d_ws;

  zero_out_k<<<(out_size + 255)/256, 256, 0, stream>>>((float*)d_out, out_size);
  setup_k<<<142, 256, 0, stream>>>(wq_w, wq_b, wk_w, wk_b, wv_w, wv_b, dense_w, ws);
  mha_fused<<<512, 256, 0, stream>>>(
      x, dense_w, dense_b,
      (const unsigned short*)(ws + 2560),   // wqT
      (const unsigned short*)(ws + 10752),  // wkT
      ws + 18944,                           // WVD
      ws + 19744,                           // bvd
      ws,                                   // pe
      (float*)d_out);
}

// Round 6
// 201.743 us; speedup vs baseline: 1.6857x; 1.0931x over previous
//
#include <hip/hip_runtime.h>

#define LOG2E 1.44269504088896340736f
#define SCL 0.18033688011111772f   // 0.125 * LOG2E

typedef __bf16 bf16x8 __attribute__((ext_vector_type(8)));
typedef float f32x16 __attribute__((ext_vector_type(16)));

union U4B { uint4 u; bf16x8 v; };

static __device__ __forceinline__ unsigned short f2bf(float f) {
  unsigned u = __builtin_bit_cast(unsigned, f);
  u += 0x7FFFu + ((u >> 16) & 1u);
  return (unsigned short)(u >> 16);
}
static __device__ __forceinline__ float bf2f(unsigned short s) {
  unsigned u = ((unsigned)s) << 16;
  return __builtin_bit_cast(float, u);
}
static __device__ __forceinline__ f32x16 zero16() {
  f32x16 z;
#pragma unroll
  for (int i = 0; i < 16; ++i) z[i] = 0.f;
  return z;
}
static __device__ __forceinline__ f32x16 MFMA(bf16x8 a, bf16x8 b, f32x16 c) {
  return __builtin_amdgcn_mfma_f32_32x32x16_bf16(a, b, c, 0, 0, 0);
}

// Transform a 32x32 C/D-layout f32x16 tile (lane: col=l&31, row=(r&3)+8*(r>>2)+4*hi)
// into two bf16x8 frags: frag[ch] elem e = T[16*ch + 8*hi + e][col].
static __device__ __forceinline__ void xform(f32x16 t, int hi, uint4& f0, uint4& f1) {
  unsigned pk[8], sw[8];
#pragma unroll
  for (int s = 0; s < 8; ++s) {
    unsigned d;
    asm("v_cvt_pk_bf16_f32 %0, %1, %2" : "=v"(d) : "v"(t[2*s]), "v"(t[2*s+1]));
    pk[s] = d;
  }
#pragma unroll
  for (int s = 0; s < 8; ++s) sw[s] = (unsigned)__shfl_xor((int)pk[s], 32);
  if (hi) {
    f0 = make_uint4(sw[2], sw[3], pk[2], pk[3]);
    f1 = make_uint4(sw[6], sw[7], pk[6], pk[7]);
  } else {
    f0 = make_uint4(pk[0], pk[1], sw[0], sw[1]);
    f1 = make_uint4(pk[4], pk[5], sw[4], sw[5]);
  }
}

__global__ void zero_out_k(float* __restrict__ out, int n) {
  int i = blockIdx.x * 256 + threadIdx.x;
  if (i < n) out[i] = 0.f;
}

__global__ void setup_k(
    const float* __restrict__ wq_w, const float* __restrict__ wq_b,
    const float* __restrict__ wk_w, const float* __restrict__ wk_b,
    const float* __restrict__ wv_w, const float* __restrict__ wv_b,
    const float* __restrict__ dense_w, float* __restrict__ ws)
{
  int gid = blockIdx.x*256 + threadIdx.x;
  float* pe = ws;                                        // 2560 f32
  unsigned short* wqT = (unsigned short*)(ws + 2560);    // [512][32] bf16 (t<20 w, t==20 bias, else 0)
  unsigned short* wkT = (unsigned short*)(ws + 10752);
  float* WVD = ws + 18944;                               // [8][10][10]
  float* bvd = ws + 19744;                               // [8][10]
  if (gid < 2560) {
    int i = gid/10, t = gid%10;
    double ex = (double)(2*(t/2)) / 10.0;
    double ang = (double)i * pow(10000.0, -ex);
    pe[gid] = (float)((t & 1) ? cos(ang) : sin(ang));
  } else if (gid < 2560 + 16384) {
    int idx = gid - 2560;
    int hd = idx >> 5, t = idx & 31;
    float v = (t < 20) ? wq_w[t*512 + hd] : ((t == 20) ? wq_b[hd] : 0.f);
    wqT[idx] = f2bf(v);
  } else if (gid < 2560 + 32768) {
    int idx = gid - (2560 + 16384);
    int hd = idx >> 5, t = idx & 31;
    float v = (t < 20) ? wk_w[t*512 + hd] : ((t == 20) ? wk_b[hd] : 0.f);
    wkT[idx] = f2bf(v);
  } else if (gid < 2560 + 32768 + 800) {
    int idx = gid - (2560 + 32768);
    int h = idx/100, rem = idx%100, t = rem/10, w = rem%10;
    float s = 0.f;
    for (int d = 0; d < 64; ++d) s += wv_w[t*512 + h*64 + d] * dense_w[(h*64 + d)*10 + w];
    WVD[idx] = s;
  } else if (gid < 2560 + 32768 + 880) {
    int idx = gid - (2560 + 32768 + 800);
    int h = idx/10, w = idx%10;
    float s = 0.f;
    for (int d = 0; d < 64; ++d) s += wv_b[h*64 + d] * dense_w[(h*64 + d)*10 + w];
    bvd[idx] = s;
  }
}

// Grid 768: block = (bc, p3). p3 handles heads {0-2},{3-5},{6-7}; atomicAdd to out.
// NOTE: __launch_bounds__ min-waves-per-EU kept at 1. Empirical 5/5 pattern:
// every build with >=2 NaN'd, every build with 1 passed (suspected codegen
// issue under forced VGPR cap with inline-asm xform; do not raise without
// a dedicated A/B).
__global__ __launch_bounds__(256, 1) void mha_fused(
    const float* __restrict__ x,
    const float* __restrict__ dense_w, const float* __restrict__ dense_b,
    const unsigned short* __restrict__ wqT, const unsigned short* __restrict__ wkT,
    const float* __restrict__ WVD, const float* __restrict__ bvd,
    const float* __restrict__ pe,
    float* __restrict__ out)
{
  __shared__ __align__(16) unsigned short qk_in[256*24];  // [win][24] bf16: dd[i+2](10), dd[i](10), 1.0, 0,0,0
  __shared__ __align__(16) unsigned short k_lds[256*64];  // [key][64] bf16 A-frags, 16B-granule XOR (key&7)
  __shared__ __align__(16) unsigned short vdT[16*256];    // [w][key] bf16, granule XOR (w&15); rows 0..9 valid
  __shared__ unsigned short mean_b[256];                  // mean*0.1 as bf16
  __shared__ unsigned long long padb[4];
  __shared__ float ddmean_s[10];

  const int tid = threadIdx.x;
  const int lane = tid & 63;
  const int wv = tid >> 6;
  const int hi = lane >> 5;
  const int cc = lane & 31;
  const int bc = blockIdx.x / 3;
  const int p3 = blockIdx.x - bc*3;
  const int hbase = p3*3;
  const int nh = (p3 == 2) ? 2 : 3;

  // ---- Phase A: load x, mean/minmask, dd = data+pe, build qk_in + padbits + ddmean ----
  float ddr[10];
  {
    const float* xb = x + ((size_t)bc*2560 + tid*10)*3;
    float dat[10], msk[10];
#pragma unroll
    for (int t = 0; t < 10; ++t) { dat[t] = xb[3*t]; msk[t] = xb[3*t+2]; }
    float mean = 0.f, mm = msk[0];
#pragma unroll
    for (int t = 0; t < 10; ++t) { mean += dat[t]*msk[t]; mm = fminf(mm, msk[t]); }
    mean_b[tid] = f2bf(mean * 0.1f);
    const float* per = pe + tid*10;
#pragma unroll
    for (int t = 0; t < 10; ++t) ddr[t] = dat[t] + per[t];
    float* ddtmp = (float*)k_lds;        // alias k_lds during phase A
    float* mmv = ddtmp + 2560;
#pragma unroll
    for (int t = 0; t < 10; ++t) ddtmp[tid*10 + t] = ddr[t];
    mmv[tid] = mm;
  }
  __syncthreads();
  {
    const float* ddtmp = (const float*)k_lds;
    const float* mmv = ddtmp + 2560;
    float* part = (float*)vdT;           // alias vdT rows 0-1 during phase A2
    if (tid < 254) {
#pragma unroll
      for (int t = 0; t < 10; ++t) qk_in[tid*24 + t] = f2bf(ddtmp[(tid+2)*10 + t]);
#pragma unroll
      for (int t = 0; t < 10; ++t) qk_in[tid*24 + 10 + t] = f2bf(ddr[t]);
      qk_in[tid*24 + 20] = 0x3F80;   // bias 1.0
      qk_in[tid*24 + 21] = 0; qk_in[tid*24 + 22] = 0; qk_in[tid*24 + 23] = 0;
    } else {
#pragma unroll
      for (int t = 0; t < 24; ++t) qk_in[tid*24 + t] = 0;
    }
    // partial sums for ddmean (mean over dd[1..254])
    if (tid < 160) {
      int t = tid >> 4, j = tid & 15;
      int w0 = 1 + j*16, w1 = (w0 + 16 < 255) ? (w0 + 16) : 255;
      float s = 0.f;
      for (int w = w0; w < w1; ++w) s += ddtmp[w*10 + t];
      part[tid] = s;
    }
    // zero vdT rows 10..15 once (never written by staging; read by PV's discarded
    // B-columns -> must not be uninitialized LDS). Disjoint from part (rows 0-1).
#pragma unroll
    for (int i = 0; i < 6; ++i) vdT[(10 + i)*256 + tid] = 0;
    // padding[key=tid] from window tid+1; keys 254/255 always masked (pad keys)
    bool cond = (tid >= 254) || (mmv[tid+1] == 0.0f);
    unsigned long long bl = __ballot(cond);
    if (lane == 0) padb[wv] = bl;
  }
  __syncthreads();
  if (tid < 10) {
    const float* part = (const float*)vdT;
    float s = 0.f;
#pragma unroll
    for (int j = 0; j < 16; ++j) s += part[tid*16 + j];
    ddmean_s[tid] = s * (1.0f/254.0f);
  }
  float dwcol = 0.f, dbias = 0.f;
  if (cc < 10) { dwcol = dense_w[5120 + cc]; dbias = dense_b[cc]; }
  const unsigned* pw = (const unsigned*)padb;

  f32x16 outacc0 = zero16(), outacc1 = zero16();

#pragma unroll 1
  for (int hh = 0; hh < nh; ++hh) {
    const int h = hbase + hh;
    __syncthreads();   // prior head's attention reads done (and phase-A LDS ready)
    // ---- stage VD^T = (dd[1..254] @ WVD_h + bvd_h)^T, bf16, swizzled ----
    if (tid < 254) {
      float df[10];
      int src = tid + 1;
      if (src <= 253) {
#pragma unroll
        for (int t = 0; t < 10; ++t) df[t] = bf2f(qk_in[src*24 + 10 + t]);   // dd[src]
      } else {
#pragma unroll
        for (int t = 0; t < 10; ++t) df[t] = bf2f(qk_in[252*24 + t]);        // dd[254]
      }
      const float* wvd = WVD + h*100;
      const float* bv = bvd + h*10;
#pragma unroll
      for (int w = 0; w < 10; ++w) {
        float s = bv[w];
#pragma unroll
        for (int t = 0; t < 10; ++t) s += df[t]*wvd[t*10 + w];
        vdT[w*256 + (tid ^ ((w & 15)*8))] = f2bf(s);
      }
    }
    if (tid < 32) {   // zero pad-keys 254/255 in rows 0..15 (avoid NaN*0 in mfma)
      int w = tid >> 1, j = 254 + (tid & 1);
      vdT[w*256 + (j ^ ((w & 15)*8))] = 0;
    }
    // meanVD for degenerate (fully-padded) query rows: colmean of VD_h
    float mvd = 0.f;
    if (cc < 10) {
      mvd = bvd[h*10 + cc];
#pragma unroll
      for (int t = 0; t < 10; ++t) mvd = fmaf(ddmean_s[t], WVD[h*100 + t*10 + cc], mvd);
    }
    __syncthreads();

    // ---- K projection (swapped): KT = WK'_h x qk_in^T, write A-frags to k_lds ----
#pragma unroll
    for (int jti = 0; jti < 2; ++jti) {
      int jt = wv + 4*jti;
      int krow = 32*jt + cc;
      U4B b0, b1;
      b0.u = *(const uint4*)&qk_in[krow*24 + 8*hi];
      b1.u = make_uint4(0,0,0,0);
      if (!hi) b1.u = *(const uint4*)&qk_in[krow*24 + 16];
#pragma unroll
      for (int it = 0; it < 2; ++it) {
        const unsigned short* wrow = wkT + (h*64 + 32*it + cc)*32;
        U4B a0, a1;
        a0.u = *(const uint4*)&wrow[8*hi];
        a1.u = *(const uint4*)&wrow[16 + 8*hi];
        f32x16 acc = zero16();
        acc = MFMA(a0.v, b0.v, acc);
        acc = MFMA(a1.v, b1.v, acc);
        uint4 f0, f1;
        xform(acc, hi, f0, f1);
        int dc0 = 2*it, dc1 = 2*it + 1;
        *(uint4*)&k_lds[krow*64 + ((8*(2*dc0 + hi)) ^ (8*(krow & 7)))] = f0;
        *(uint4*)&k_lds[krow*64 + ((8*(2*dc1 + hi)) ^ (8*(krow & 7)))] = f1;
      }
    }
    __syncthreads();

    // ---- attention: wave wv owns query tiles {wv, 7-wv} (causal work = 9 tiles, balanced) ----
#pragma unroll
    for (int qti = 0; qti < 2; ++qti) {
      const int qt = qti ? (7 - wv) : wv;
      const int qrow = 32*qt + cc;
      // Q projection (swapped) -> B-frags in regs
      uint4 qf0, qf1, qf2, qf3;
      {
        U4B b0, b1;
        b0.u = *(const uint4*)&qk_in[qrow*24 + 8*hi];
        b1.u = make_uint4(0,0,0,0);
        if (!hi) b1.u = *(const uint4*)&qk_in[qrow*24 + 16];
        {
          const unsigned short* wrow = wqT + (h*64 + cc)*32;
          U4B a0, a1;
          a0.u = *(const uint4*)&wrow[8*hi];
          a1.u = *(const uint4*)&wrow[16 + 8*hi];
          f32x16 acc = zero16();
          acc = MFMA(a0.v, b0.v, acc);
          acc = MFMA(a1.v, b1.v, acc);
          xform(acc, hi, qf0, qf1);
        }
        {
          const unsigned short* wrow = wqT + (h*64 + 32 + cc)*32;
          U4B a0, a1;
          a0.u = *(const uint4*)&wrow[8*hi];
          a1.u = *(const uint4*)&wrow[16 + 8*hi];
          f32x16 acc = zero16();
          acc = MFMA(a0.v, b0.v, acc);
          acc = MFMA(a1.v, b1.v, acc);
          xform(acc, hi, qf2, qf3);
        }
      }
      // ---- single-pass masked-exp softmax (m = 0; logits are tiny) + PV ----
      float sum = 0.f;
      f32x16 pv = zero16();
      const int vrow = cc & 15;
      const int vsw = 8*vrow;
#pragma unroll
      for (int kt = 0; kt < 8; ++kt) {
        if (kt <= qt) {
          const int kr = 32*kt + cc;
          const int kbase = kr*64;
          const int ksw = 8*(kr & 7);
          f32x16 a = zero16();
          U4B ka, qa;
          ka.u = *(const uint4*)&k_lds[kbase + ((8*(0 + hi)) ^ ksw)];
          qa.u = qf0; a = MFMA(ka.v, qa.v, a);
          ka.u = *(const uint4*)&k_lds[kbase + ((8*(2 + hi)) ^ ksw)];
          qa.u = qf1; a = MFMA(ka.v, qa.v, a);
          ka.u = *(const uint4*)&k_lds[kbase + ((8*(4 + hi)) ^ ksw)];
          qa.u = qf2; a = MFMA(ka.v, qa.v, a);
          ka.u = *(const uint4*)&k_lds[kbase + ((8*(6 + hi)) ^ ksw)];
          qa.u = qf3; a = MFMA(ka.v, qa.v, a);
          const unsigned pbk = pw[kt];
          if (kt < qt) {        // non-diagonal: padding mask only
#pragma unroll
            for (int r = 0; r < 16; ++r) {
              const int base = (r & 3) + 8*(r >> 2);
              const int pos = base + 4*hi;
              float add = ((pbk >> pos) & 1u) ? -2.0e9f : 0.0f;
              float p = exp2f(fmaf(a[r], SCL, add));
              a[r] = p;
              sum += p;
            }
          } else {              // diagonal: padding + causal
#pragma unroll
            for (int r = 0; r < 16; ++r) {
              const int base = (r & 3) + 8*(r >> 2);
              const int pos = base + 4*hi;
              bool mk = (((pbk >> pos) & 1u) != 0u) || (pos > cc);
              float add = mk ? -2.0e9f : 0.0f;
              float p = exp2f(fmaf(a[r], SCL, add));
              a[r] = p;
              sum += p;
            }
          }
          // P -> A-frags, PV MFMA
          uint4 pa0, pa1;
          xform(a, hi, pa0, pa1);
          U4B pA, vB;
          pA.u = pa0;
          vB.u = *(const uint4*)&vdT[vrow*256 + ((32*kt + 8*hi) ^ vsw)];
          pv = MFMA(pA.v, vB.v, pv);
          pA.u = pa1;
          vB.u = *(const uint4*)&vdT[vrow*256 + ((32*kt + 16 + 8*hi) ^ vsw)];
          pv = MFMA(pA.v, vB.v, pv);
        }
      }
      float stot = sum + __shfl_xor(sum, 32);
      // clamp: degenerate rows give stot==0; keep rs finite (0*rs=0), degq select
      // below substitutes mvd. No inf/NaN on any path.
      const float rs = 1.0f / fmaxf(stot, 1e-30f);
      // ---- degenerate (all keys <= q padded) -> substitute column-mean of VD ----
      bool pre = true;
#pragma unroll
      for (int j = 0; j < 8; ++j) { if (j < qt) pre = pre && (pw[j] == 0xFFFFFFFFu); }
      const unsigned pbq = pw[qt];
#pragma unroll
      for (int r = 0; r < 16; ++r) {
        const int base = (r & 3) + 8*(r >> 2);
        const int qr = base + 4*hi;
        unsigned lm = (qr == 31) ? 0xFFFFFFFFu : ((2u << qr) - 1u);
        bool degq = pre && ((pbq & lm) == lm);
        float rr = __shfl(rs, qr, 32);
        float contrib = degq ? mvd : pv[r]*rr;
        if (qti == 0) outacc0[r] += contrib; else outacc1[r] += contrib;
      }
    }
  }

  // ---- epilogue: atomicAdd partial sums; p3 0 adds mean term + bias ----
#pragma unroll
  for (int qti = 0; qti < 2; ++qti) {
    const int qt = qti ? (7 - wv) : wv;
#pragma unroll
    for (int r = 0; r < 16; ++r) {
      const int base = (r & 3) + 8*(r >> 2);
      int q = 32*qt + base + 4*hi;
      if (q < 254 && cc < 10) {
        float v = (qti == 0 ? outacc0[r] : outacc1[r]);
        if (p3 == 0) v += bf2f(mean_b[q + 1])*dwcol + dbias;
        atomicAdd(&out[((size_t)bc*254 + q)*10 + cc], v);
      }
    }
  }
}

extern "C" void kernel_launch(void* const* d_in, const int* in_sizes, int n_in,
                              void* d_out, int out_size, void* d_ws, size_t ws_size,
                              hipStream_t stream) {
  const float* x       = (const float*)d_in[0];
  const float* wq_w    = (const float*)d_in[1];
  const float* wq_b    = (const float*)d_in[2];
  const float* wk_w    = (const float*)d_in[3];
  const float* wk_b    = (const float*)d_in[4];
  const float* wv_w    = (const float*)d_in[5];
  const float* wv_b    = (const float*)d_in[6];
  const float* dense_w = (const float*)d_in[7];
  const float* dense_b = (const float*)d_in[8];
  float* ws = (float*)d_ws;

  zero_out_k<<<(out_size + 255)/256, 256, 0, stream>>>((float*)d_out, out_size);
  setup_k<<<142, 256, 0, stream>>>(wq_w, wq_b, wk_w, wk_b, wv_w, wv_b, dense_w, ws);
  mha_fused<<<768, 256, 0, stream>>>(
      x, dense_w, dense_b,
      (const unsigned short*)(ws + 2560),   // wqT
      (const unsigned short*)(ws + 10752),  // wkT
      ws + 18944,                           // WVD
      ws + 19744,                           // bvd
      ws,                                   // pe
      (float*)d_out);
}